// Round 5
// baseline (575.573 us; speedup 1.0000x reference)
//
#include <hip/hip_runtime.h>
#include <hip/hip_bf16.h>
#include <math.h>

#define B_   4
#define L_   2048
#define E_   1024
#define H_   16
#define DH_  64
#define HID_ 1024
#define ROWS (B_*L_)      // 8192
#define NCH  16
#define CLEN (L_/NCH)     // 128

typedef __attribute__((ext_vector_type(8))) short short8;
typedef __attribute__((ext_vector_type(4))) float f32x4;

__device__ __forceinline__ unsigned short f2bf(float f) {
  union { float f; unsigned int i; } v; v.f = f;
  unsigned int r = v.i + 0x7fffu + ((v.i >> 16) & 1u);
  return (unsigned short)(r >> 16);
}
__device__ __forceinline__ float bf2f(unsigned int u) {
  union { unsigned int i; float f; } v; v.i = u << 16; return v.f;
}

__device__ __forceinline__ void gload16(const unsigned short* g, unsigned short* l) {
  __builtin_amdgcn_global_load_lds((const __attribute__((address_space(1))) void*)g,
                                   (__attribute__((address_space(3))) void*)l, 16, 0, 0);
}

// ---------------- elementwise cast f32 -> bf16 (4/thread) ----------------
__global__ void cast_f32_bf16(const float* __restrict__ src, unsigned short* __restrict__ dst, int n) {
  int i = (blockIdx.x * 256 + threadIdx.x) * 4;
  if (i < n) {
    float4 v = *(const float4*)(src + i);
    ushort4 o;
    o.x = f2bf(v.x); o.y = f2bf(v.y); o.z = f2bf(v.z); o.w = f2bf(v.w);
    *(ushort4*)(dst + i) = o;
  }
}

// ---------------- tiled transpose + cast ----------------
__global__ void transpose_cast(const float* __restrict__ src, unsigned short* __restrict__ dst,
                               int R, int C, int dstBase) {
  __shared__ float tile[32][33];
  src += (size_t)blockIdx.z * R * C;
  int dstRow0 = dstBase + blockIdx.z * C;
  int rb = blockIdx.x * 32, cb = blockIdx.y * 32;
  for (int i = threadIdx.y; i < 32; i += 8)
    tile[i][threadIdx.x] = src[(size_t)(rb + i) * C + cb + threadIdx.x];
  __syncthreads();
  for (int i = threadIdx.y; i < 32; i += 8)
    dst[(size_t)(dstRow0 + cb + i) * R + rb + threadIdx.x] = f2bf(tile[threadIdx.x][i]);
}

// ---------------- concat bias [ba|bb|bD] ----------------
__global__ void build_bias(const float* __restrict__ ba, const float* __restrict__ bb,
                           const float* __restrict__ bD, float* __restrict__ bias) {
  int i = blockIdx.x * 256 + threadIdx.x;
  const float* src = (i < 1024) ? ba : ((i < 2048) ? bb : bD);
  bias[i] = src[i & 1023];
}

// ---------------- compact diag WC^T: wcd[c][kl] (1024 x 128) ----------------
__global__ void build_wcd(const float* __restrict__ WC, unsigned short* __restrict__ dst) {
  int i = blockIdx.x * 256 + threadIdx.x;     // over 1024*128
  int c = i >> 7, kl = i & 127;
  float v = ((kl >> 6) == ((c >> 6) & 1)) ? WC[(size_t)(c >> 6) * 4096 + (kl & 63) * 64 + (c & 63)] : 0.f;
  dst[i] = f2bf(v);
}

// ---------------- fused epilogues ----------------
#define EPI_GATES 0   // bf16: a->out interleaved(2c), b->out(2c+1), d->out2; tanh on a
#define EPI_GELU  1   // bf16 out; exact gelu
#define EPI_RES   2   // bf16 out; + aux (f32 residual, stride N)
#define EPI_OUT   3   // f32 out
#define EPI_HEAD  4   // f32 out; (acc+bias)*aux  (aux bf16, stride 1024)

template<int EPI>
__device__ __forceinline__ void epi_store(float xa, int rr, int cc, int N,
                                          const float* __restrict__ bias,
                                          const void* __restrict__ aux,
                                          void* __restrict__ out, void* __restrict__ out2) {
  float x = xa + bias[cc];
  if (EPI == EPI_GATES) {
    if (cc < HID_) {
      x = tanhf(x);
      ((unsigned short*)out)[(size_t)rr * 2048 + (cc << 1)] = f2bf(x);
    } else if (cc < 2048) {
      ((unsigned short*)out)[(size_t)rr * 2048 + ((cc - 1024) << 1) + 1] = f2bf(x);
    } else {
      ((unsigned short*)out2)[(size_t)rr * 1024 + (cc - 2048)] = f2bf(x);
    }
  } else if (EPI == EPI_GELU) {
    x = 0.5f * x * (1.f + erff(x * 0.70710678118654752f));
    ((unsigned short*)out)[(size_t)rr * N + cc] = f2bf(x);
  } else if (EPI == EPI_RES) {
    x += ((const float*)aux)[(size_t)rr * N + cc];
    ((unsigned short*)out)[(size_t)rr * N + cc] = f2bf(x);
  } else if (EPI == EPI_HEAD) {
    x *= bf2f(((const unsigned short*)aux)[(size_t)rr * 1024 + cc]);
    ((float*)out)[(size_t)rr * N + cc] = x;
  } else {
    ((float*)out)[(size_t)rr * N + cc] = x;
  }
}

// ---------------- 128x128 m97-structure GEMM with strides + diag offset ----------------
template<int EPI, int DIAG>
__global__ __launch_bounds__(256)
void gemm_bt(const unsigned short* __restrict__ A, int lda,
             const unsigned short* __restrict__ Bt, int ldb,
             const float* __restrict__ bias, const void* __restrict__ aux,
             void* __restrict__ out, void* __restrict__ out2, int M, int N, int K) {
  __shared__ unsigned short lA[128 * 32];
  __shared__ unsigned short lB[128 * 32];
  const int tid = threadIdx.x;
  const int w = tid >> 6, l = tid & 63;
  // T1 XCD swizzle (nwg % 8 == 0)
  const int gx = gridDim.x, nwg = gx * gridDim.y;
  const int o = blockIdx.y * gx + blockIdx.x;
  const int lin = (o & 7) * (nwg >> 3) + (o >> 3);
  const int row0 = (lin / gx) * 128, col0 = (lin % gx) * 128;
  const int kOff = DIAG ? col0 : 0;

  const int rA0 = w * 16 + (l >> 2);
  const int rA1 = (4 + w) * 16 + (l >> 2);
  const int koff = (l & 3) * 8;
  const unsigned short* gA0 = A + (size_t)(row0 + rA0) * lda + kOff + koff;
  const unsigned short* gA1 = A + (size_t)(row0 + rA1) * lda + kOff + koff;
  const unsigned short* gB0 = Bt + (size_t)(col0 + rA0) * ldb + koff;
  const unsigned short* gB1 = Bt + (size_t)(col0 + rA1) * ldb + koff;
  unsigned short* lA0 = lA + w * 512;
  unsigned short* lA1 = lA + (4 + w) * 512;
  unsigned short* lB0 = lB + w * 512;
  unsigned short* lB1 = lB + (4 + w) * 512;

  const int wr = (w >> 1) * 64, wc = (w & 1) * 64;
  f32x4 acc[4][4];
  #pragma unroll
  for (int m = 0; m < 4; m++)
    #pragma unroll
    for (int n = 0; n < 4; n++) acc[m][n] = (f32x4){0.f, 0.f, 0.f, 0.f};

  const int arow = wr + (l & 15);
  const int brow = wc + (l & 15);
  const int kg = (l >> 4) * 8;

  for (int kt = 0; kt < K; kt += 32) {
    __syncthreads();
    gload16(gA0 + kt, lA0);
    gload16(gA1 + kt, lA1);
    gload16(gB0 + kt, lB0);
    gload16(gB1 + kt, lB1);
    __syncthreads();
    short8 af[4], bfr[4];
    #pragma unroll
    for (int m = 0; m < 4; m++) af[m]  = *(const short8*)(lA + (arow + m * 16) * 32 + kg);
    #pragma unroll
    for (int n = 0; n < 4; n++) bfr[n] = *(const short8*)(lB + (brow + n * 16) * 32 + kg);
    #pragma unroll
    for (int m = 0; m < 4; m++)
      #pragma unroll
      for (int n = 0; n < 4; n++)
        acc[m][n] = __builtin_amdgcn_mfma_f32_16x16x32_bf16(af[m], bfr[n], acc[m][n], 0, 0, 0);
  }

  const int er = row0 + wr + ((l >> 4) << 2);
  const int ec = col0 + wc + (l & 15);
  #pragma unroll
  for (int m = 0; m < 4; m++)
    #pragma unroll
    for (int n = 0; n < 4; n++)
      #pragma unroll
      for (int j = 0; j < 4; j++)
        epi_store<EPI>(acc[m][n][j], er + m * 16 + j, ec + n * 16, N, bias, aux, out, out2);
}

// ---------------- 256x256 barrier-light GEMM v2 ----------------
// Per K-tile(64): all 24 ds_read_b128 issued up front, 64 MFMA, NO internal barriers
// (compiler inserts counted lgkmcnt; waves drift -> LDS/MFMA pipes overlap).
// 2 barriers/tile at staging boundary; distance-2 prefetch; counted vmcnt(8).
template<int EPI>
__global__ __launch_bounds__(512, 2)
void gemm256v2(const unsigned short* __restrict__ A, const unsigned short* __restrict__ Bt,
               const float* __restrict__ bias, const void* __restrict__ aux,
               void* __restrict__ out, void* __restrict__ out2, int M, int N, int K) {
  __shared__ unsigned short lds[2][2][256 * 64];
  const int tid = threadIdx.x;
  const int w = tid >> 6, l = tid & 63;
  const int wm = w >> 2, wn = w & 3;          // 2M x 4N waves, per-wave 128x64
  const int gx = gridDim.x, nwg = gx * gridDim.y;
  const int o = blockIdx.y * gx + blockIdx.x;
  const int lin = (o & 7) * (nwg >> 3) + (o >> 3);
  const int row0 = (lin / gx) * 256, col0 = (lin % gx) * 256;
  const int lr = l & 15, kg = (l >> 4) << 3;
  const int wmb = wm * 128, wnb = wn * 64;
  const int nT = K >> 6;

  const int srow = w * 8 + (l >> 3);
  const int kswz = (((l & 7) ^ (l >> 3)) << 3);

  f32x4 acc[8][4];
  #pragma unroll
  for (int m = 0; m < 8; m++)
    #pragma unroll
    for (int n = 0; n < 4; n++) acc[m][n] = (f32x4){0.f, 0.f, 0.f, 0.f};

  auto stage = [&](int buf, int kt) {   // full 256x64 A+B tile: 8 gloads
    const unsigned short* ga = A + (size_t)(row0 + srow) * K + kt * 64 + kswz;
    const unsigned short* gb = Bt + (size_t)(col0 + srow) * K + kt * 64 + kswz;
    unsigned short* da = &lds[buf][0][w * 512];
    unsigned short* db = &lds[buf][1][w * 512];
    gload16(ga, da);
    gload16(ga + (size_t)64 * K, da + 4096);
    gload16(ga + (size_t)128 * K, da + 8192);
    gload16(ga + (size_t)192 * K, da + 12288);
    gload16(gb, db);
    gload16(gb + (size_t)64 * K, db + 4096);
    gload16(gb + (size_t)128 * K, db + 8192);
    gload16(gb + (size_t)192 * K, db + 12288);
  };

  // prologue: tiles 0 and 1; drain tile0 only
  stage(0, 0);
  stage(1, 1);
  asm volatile("s_waitcnt vmcnt(8)" ::: "memory");
  __builtin_amdgcn_s_barrier();

  for (int t = 0; t < nT; ++t) {
    const int buf = t & 1;
    const unsigned short* LA = lds[buf][0];
    const unsigned short* LB = lds[buf][1];

    short8 fa0[4][2], fa1[4][2], fb[2][2][2];
    // B fragments (8 reads) + A lower half (8) first, A upper half (8) after
    #pragma unroll
    for (int nh = 0; nh < 2; ++nh)
      #pragma unroll
      for (int nf = 0; nf < 2; ++nf)
        #pragma unroll
        for (int ks = 0; ks < 2; ++ks) {
          int r = wnb + nh * 32 + nf * 16 + lr; int k = ks * 32 + kg;
          fb[nh][nf][ks] = *(const short8*)(LB + r * 64 + (k ^ ((r & 7) << 3)));
        }
    #pragma unroll
    for (int mf = 0; mf < 4; ++mf)
      #pragma unroll
      for (int ks = 0; ks < 2; ++ks) {
        int r = wmb + mf * 16 + lr; int k = ks * 32 + kg;
        fa0[mf][ks] = *(const short8*)(LA + r * 64 + (k ^ ((r & 7) << 3)));
      }
    #pragma unroll
    for (int mf = 0; mf < 4; ++mf)
      #pragma unroll
      for (int ks = 0; ks < 2; ++ks) {
        int r = wmb + 64 + mf * 16 + lr; int k = ks * 32 + kg;
        fa1[mf][ks] = *(const short8*)(LA + r * 64 + (k ^ ((r & 7) << 3)));
      }

    __builtin_amdgcn_s_setprio(1);
    #pragma unroll
    for (int nh = 0; nh < 2; ++nh)
      #pragma unroll
      for (int nf = 0; nf < 2; ++nf)
        #pragma unroll
        for (int mf = 0; mf < 4; ++mf)
          #pragma unroll
          for (int ks = 0; ks < 2; ++ks)
            acc[mf][nh * 2 + nf] = __builtin_amdgcn_mfma_f32_16x16x32_bf16(
                fa0[mf][ks], fb[nh][nf][ks], acc[mf][nh * 2 + nf], 0, 0, 0);
    #pragma unroll
    for (int nh = 0; nh < 2; ++nh)
      #pragma unroll
      for (int nf = 0; nf < 2; ++nf)
        #pragma unroll
        for (int mf = 0; mf < 4; ++mf)
          #pragma unroll
          for (int ks = 0; ks < 2; ++ks)
            acc[4 + mf][nh * 2 + nf] = __builtin_amdgcn_mfma_f32_16x16x32_bf16(
                fa1[mf][ks], fb[nh][nf][ks], acc[4 + mf][nh * 2 + nf], 0, 0, 0);
    __builtin_amdgcn_s_setprio(0);

    __builtin_amdgcn_s_barrier();            // all waves done reading buf
    if (t + 2 < nT) {
      stage(buf, t + 2);                     // overwrite just-consumed buf
      asm volatile("s_waitcnt vmcnt(8)" ::: "memory");   // tile t+1 resident
    } else {
      asm volatile("s_waitcnt vmcnt(0)" ::: "memory");   // drain tail
    }
    __builtin_amdgcn_s_barrier();            // every wave confirmed t+1 staging
  }

  const int er = row0 + wmb + ((l >> 4) << 2);
  const int ec = col0 + wnb + lr;
  #pragma unroll
  for (int mi = 0; mi < 8; ++mi)
    #pragma unroll
    for (int ni = 0; ni < 4; ++ni)
      #pragma unroll
      for (int j = 0; j < 4; ++j)
        epi_store<EPI>(acc[mi][ni][j], er + mi * 16 + j, ec + ni * 16, N, bias, aux, out, out2);
}

// ---------------- chunked affine scan (bf16 inputs, f32 accum) ----------------
__global__ void scan_p1(const unsigned short* __restrict__ ab16, float* __restrict__ aggA, float* __restrict__ aggB) {
  int id = blockIdx.x * 256 + threadIdx.x;
  int c = id & 1023;
  int chunk = (id >> 10) & (NCH - 1);
  int bb = id >> 14;
  const unsigned short* base = ab16 + (size_t)(bb * L_ + chunk * CLEN) * 2048 + 2 * c;
  float Aa = 1.f, Bv = 0.f;
  #pragma unroll 4
  for (int t = 0; t < CLEN; ++t) {
    unsigned int v = *(const unsigned int*)(base + (size_t)t * 2048);
    float a = bf2f(v & 0xffffu);
    float b = bf2f(v >> 16);
    Aa *= a;
    Bv = a * Bv + b;
  }
  int o = (chunk * B_ + bb) * 1024 + c;
  aggA[o] = Aa; aggB[o] = Bv;
}

__global__ void scan_p2(const float* __restrict__ aggA, const float* __restrict__ aggB,
                        float* __restrict__ hinit) {
  int id = blockIdx.x * 256 + threadIdx.x;
  float hc = 0.f;
  for (int ch = 0; ch < NCH; ++ch) {
    int o = ch * 4096 + id;
    hinit[o] = hc;
    hc = aggA[o] * hc + aggB[o];
  }
}

__global__ void scan_p3(const unsigned short* __restrict__ ab16, const float* __restrict__ hinit,
                        unsigned short* __restrict__ hb16) {
  int id = blockIdx.x * 256 + threadIdx.x;
  int c = id & 1023;
  int chunk = (id >> 10) & (NCH - 1);
  int bb = id >> 14;
  const unsigned short* base = ab16 + (size_t)(bb * L_ + chunk * CLEN) * 2048 + 2 * c;
  unsigned short* hb = hb16 + (size_t)(bb * L_ + chunk * CLEN) * 1024;
  float h = hinit[chunk * 4096 + bb * 1024 + c];
  #pragma unroll 4
  for (int t = 0; t < CLEN; ++t) {
    unsigned int v = *(const unsigned int*)(base + (size_t)t * 2048);
    float a = bf2f(v & 0xffffu);
    float b = bf2f(v >> 16);
    h = a * h + b;
    hb[(size_t)t * 1024 + c] = f2bf(h);
  }
}

// ---------------- u = z + LN(z); outputs f32 + bf16 ----------------
__global__ __launch_bounds__(256)
void ln_res(const float* __restrict__ z, const float* __restrict__ lg, const float* __restrict__ lb,
            float* __restrict__ u32, unsigned short* __restrict__ u16) {
  int row = blockIdx.x;
  int t = threadIdx.x;
  const float4 zv = *(const float4*)(z + (size_t)row * 1024 + t * 4);
  float s = zv.x + zv.y + zv.z + zv.w;
  float sq = zv.x * zv.x + zv.y * zv.y + zv.z * zv.z + zv.w * zv.w;
  #pragma unroll
  for (int o = 32; o > 0; o >>= 1) { s += __shfl_down(s, o); sq += __shfl_down(sq, o); }
  __shared__ float ps[4], pq[4];
  if ((t & 63) == 0) { ps[t >> 6] = s; pq[t >> 6] = sq; }
  __syncthreads();
  s = ps[0] + ps[1] + ps[2] + ps[3];
  sq = pq[0] + pq[1] + pq[2] + pq[3];
  float mu = s * (1.f / 1024.f);
  float var = sq * (1.f / 1024.f) - mu * mu;
  float rs = rsqrtf(var + 1e-5f);
  const float4 gv = *(const float4*)(lg + t * 4);
  const float4 bv = *(const float4*)(lb + t * 4);
  float4 o;
  o.x = zv.x + (zv.x - mu) * rs * gv.x + bv.x;
  o.y = zv.y + (zv.y - mu) * rs * gv.y + bv.y;
  o.z = zv.z + (zv.z - mu) * rs * gv.z + bv.z;
  o.w = zv.w + (zv.w - mu) * rs * gv.w + bv.w;
  *(float4*)(u32 + (size_t)row * 1024 + t * 4) = o;
  ushort4 ob; ob.x = f2bf(o.x); ob.y = f2bf(o.y); ob.z = f2bf(o.z); ob.w = f2bf(o.w);
  *(ushort4*)(u16 + (size_t)row * 1024 + t * 4) = ob;
}

extern "C" void kernel_launch(void* const* d_in, const int* in_sizes, int n_in,
                              void* d_out, int out_size, void* d_ws, size_t ws_size,
                              hipStream_t stream) {
  const float* emb    = (const float*)d_in[0];
  const float* Wa     = (const float*)d_in[1];
  const float* ba     = (const float*)d_in[2];
  const float* Wb     = (const float*)d_in[3];
  const float* bb     = (const float*)d_in[4];
  const float* WD     = (const float*)d_in[5];
  const float* bD     = (const float*)d_in[6];
  const float* WC     = (const float*)d_in[7];
  const float* bC     = (const float*)d_in[8];
  const float* ffn1_w = (const float*)d_in[9];
  const float* ffn1_b = (const float*)d_in[10];
  const float* ffn2_w = (const float*)d_in[11];
  const float* ffn2_b = (const float*)d_in[12];
  const float* proj_w = (const float*)d_in[13];
  const float* proj_b = (const float*)d_in[14];
  const float* ln_g   = (const float*)d_in[15];
  const float* ln_b   = (const float*)d_in[16];

  char* p = (char*)d_ws;
  auto alloc = [&](size_t bytes) { char* r = p; p += (bytes + 255) & ~(size_t)255; return (void*)r; };

  unsigned short* ab16 = (unsigned short*)alloc((size_t)ROWS * 2048 * 2);  // 32MB (a,b) pairs
  unsigned short* d16  = (unsigned short*)alloc((size_t)ROWS * 1024 * 2);  // 16MB d gate
  unsigned short* hb16 = (unsigned short*)alloc((size_t)ROWS * 1024 * 2);  // 16MB scan h
  float* zbuf  = (float*)alloc((size_t)ROWS * 1024 * 4);                   // 32MB
  float* u32   = (float*)alloc((size_t)ROWS * 1024 * 4);
  unsigned short* u16  = (unsigned short*)alloc((size_t)ROWS * 1024 * 2);
  unsigned short* embb = (unsigned short*)alloc((size_t)ROWS * 1024 * 2);
  unsigned short* wcat = (unsigned short*)alloc((size_t)3072 * 1024 * 2);
  unsigned short* f1t  = (unsigned short*)alloc((size_t)4096 * 1024 * 2);
  unsigned short* f2t  = (unsigned short*)alloc((size_t)4096 * 1024 * 2);
  unsigned short* pjt  = (unsigned short*)alloc((size_t)1024 * 1024 * 2);
  unsigned short* wcd  = (unsigned short*)alloc((size_t)1024 * 128 * 2);
  float* biascat = (float*)alloc(3072 * 4);
  float* aggA  = (float*)alloc(65536 * 4);
  float* aggB  = (float*)alloc(65536 * 4);
  float* hinit = (float*)alloc(65536 * 4);
  // aliases (disjoint lifetimes):
  unsigned short* gbuf = ab16;                  // [ROWS][4096] bf16, written by FFN1 (after head)
  unsigned short* vbuf = (unsigned short*)zbuf; // [ROWS][1024] bf16, written by FFN2 (after ln_res)

  dim3 tb(32, 8);
  cast_f32_bf16<<<ROWS * 1024 / 1024, 256, 0, stream>>>(emb, embb, ROWS * 1024);
  build_bias<<<12, 256, 0, stream>>>(ba, bb, bD, biascat);
  build_wcd<<<1024 * 128 / 256, 256, 0, stream>>>(WC, wcd);
  transpose_cast<<<dim3(E_ / 32, DH_ / 32, H_), tb, 0, stream>>>(Wa, wcat, E_, DH_, 0);
  transpose_cast<<<dim3(E_ / 32, DH_ / 32, H_), tb, 0, stream>>>(Wb, wcat, E_, DH_, 1024);
  transpose_cast<<<dim3(E_ / 32, DH_ / 32, H_), tb, 0, stream>>>(WD, wcat, E_, DH_, 2048);
  transpose_cast<<<dim3(1024 / 32, 4096 / 32, 1), tb, 0, stream>>>(ffn1_w, f1t, 1024, 4096, 0);
  transpose_cast<<<dim3(4096 / 32, 1024 / 32, 1), tb, 0, stream>>>(ffn2_w, f2t, 4096, 1024, 0);
  transpose_cast<<<dim3(1024 / 32, 1024 / 32, 1), tb, 0, stream>>>(proj_w, pjt, 1024, 1024, 0);

  // G1: [8192,1024]x[1024,3072] -> ab16 + d16   [256^2 v2]
  gemm256v2<EPI_GATES><<<dim3(3072 / 256, ROWS / 256), 512, 0, stream>>>(
      embb, wcat, biascat, nullptr, ab16, d16, ROWS, 3072, 1024);

  scan_p1<<<65536 / 256, 256, 0, stream>>>(ab16, aggA, aggB);
  scan_p2<<<4096 / 256, 256, 0, stream>>>(aggA, aggB, hinit);
  scan_p3<<<65536 / 256, 256, 0, stream>>>(ab16, hinit, hb16);

  // head: z = (h @ WC_diag + bC) * d ; K=128 diag window per col-block
  gemm_bt<EPI_HEAD, 1><<<dim3(1024 / 128, ROWS / 128), 256, 0, stream>>>(
      hb16, 1024, wcd, 128, bC, d16, zbuf, nullptr, ROWS, 1024, 128);

  ln_res<<<ROWS, 256, 0, stream>>>(zbuf, ln_g, ln_b, u32, u16);

  // FFN1: [8192,1024]x[1024,4096] -> gelu -> gbuf   [256^2 v2]
  gemm256v2<EPI_GELU><<<dim3(4096 / 256, ROWS / 256), 512, 0, stream>>>(
      u16, f1t, ffn1_b, nullptr, gbuf, nullptr, ROWS, 4096, 1024);
  // FFN2: [8192,4096]x[4096,1024] + u -> vbuf       [128^2 m97 + XCD swizzle]
  gemm_bt<EPI_RES, 0><<<dim3(1024 / 128, ROWS / 128), 256, 0, stream>>>(
      gbuf, 4096, f2t, 4096, ffn2_b, u32, vbuf, nullptr, ROWS, 1024, 4096);
  // proj: [8192,1024]x[1024,1024] -> d_out (f32)    [128^2 m97 + XCD swizzle]
  gemm_bt<EPI_OUT, 0><<<dim3(1024 / 128, ROWS / 128), 256, 0, stream>>>(
      vbuf, 1024, pjt, 1024, proj_b, nullptr, (float*)d_out, nullptr, ROWS, 1024, 1024);
}

// Round 6
// 568.495 us; speedup vs baseline: 1.0124x; 1.0124x over previous
//
#include <hip/hip_runtime.h>
#include <hip/hip_bf16.h>
#include <math.h>

#define B_   4
#define L_   2048
#define E_   1024
#define H_   16
#define DH_  64
#define HID_ 1024
#define ROWS (B_*L_)      // 8192
#define NCH  16
#define CLEN (L_/NCH)     // 128

typedef __attribute__((ext_vector_type(8))) short short8;
typedef __attribute__((ext_vector_type(4))) float f32x4;

__device__ __forceinline__ unsigned short f2bf(float f) {
  union { float f; unsigned int i; } v; v.f = f;
  unsigned int r = v.i + 0x7fffu + ((v.i >> 16) & 1u);
  return (unsigned short)(r >> 16);
}
__device__ __forceinline__ float bf2f(unsigned int u) {
  union { unsigned int i; float f; } v; v.i = u << 16; return v.f;
}

__device__ __forceinline__ void gload16(const unsigned short* g, unsigned short* l) {
  __builtin_amdgcn_global_load_lds((const __attribute__((address_space(1))) void*)g,
                                   (__attribute__((address_space(3))) void*)l, 16, 0, 0);
}

// ---------------- elementwise cast f32 -> bf16 (4/thread) ----------------
__global__ void cast_f32_bf16(const float* __restrict__ src, unsigned short* __restrict__ dst, int n) {
  int i = (blockIdx.x * 256 + threadIdx.x) * 4;
  if (i < n) {
    float4 v = *(const float4*)(src + i);
    ushort4 o;
    o.x = f2bf(v.x); o.y = f2bf(v.y); o.z = f2bf(v.z); o.w = f2bf(v.w);
    *(ushort4*)(dst + i) = o;
  }
}

// ---------------- tiled transpose + cast ----------------
__global__ void transpose_cast(const float* __restrict__ src, unsigned short* __restrict__ dst,
                               int R, int C, int dstBase) {
  __shared__ float tile[32][33];
  src += (size_t)blockIdx.z * R * C;
  int dstRow0 = dstBase + blockIdx.z * C;
  int rb = blockIdx.x * 32, cb = blockIdx.y * 32;
  for (int i = threadIdx.y; i < 32; i += 8)
    tile[i][threadIdx.x] = src[(size_t)(rb + i) * C + cb + threadIdx.x];
  __syncthreads();
  for (int i = threadIdx.y; i < 32; i += 8)
    dst[(size_t)(dstRow0 + cb + i) * R + rb + threadIdx.x] = f2bf(tile[threadIdx.x][i]);
}

// ---------------- concat bias [ba|bb|bD] ----------------
__global__ void build_bias(const float* __restrict__ ba, const float* __restrict__ bb,
                           const float* __restrict__ bD, float* __restrict__ bias) {
  int i = blockIdx.x * 256 + threadIdx.x;
  const float* src = (i < 1024) ? ba : ((i < 2048) ? bb : bD);
  bias[i] = src[i & 1023];
}

// ---------------- compact diag WC^T: wcd[c][kl] (1024 x 128) ----------------
__global__ void build_wcd(const float* __restrict__ WC, unsigned short* __restrict__ dst) {
  int i = blockIdx.x * 256 + threadIdx.x;     // over 1024*128
  int c = i >> 7, kl = i & 127;
  float v = ((kl >> 6) == ((c >> 6) & 1)) ? WC[(size_t)(c >> 6) * 4096 + (kl & 63) * 64 + (c & 63)] : 0.f;
  dst[i] = f2bf(v);
}

// ---------------- fused epilogues ----------------
#define EPI_GATES 0   // bf16: a->out interleaved(2c), b->out(2c+1), d->out2; tanh on a
#define EPI_GELU  1   // bf16 out; exact gelu
#define EPI_RES   2   // bf16 out; + aux (f32 residual, stride N)
#define EPI_OUT   3   // f32 out
#define EPI_HEAD  4   // f32 out; (acc+bias)*aux  (aux bf16, stride 1024)

template<int EPI>
__device__ __forceinline__ void epi_store(float xa, int rr, int cc, int N,
                                          const float* __restrict__ bias,
                                          const void* __restrict__ aux,
                                          void* __restrict__ out, void* __restrict__ out2) {
  float x = xa + bias[cc];
  if (EPI == EPI_GATES) {
    if (cc < HID_) {
      x = tanhf(x);
      ((unsigned short*)out)[(size_t)rr * 2048 + (cc << 1)] = f2bf(x);
    } else if (cc < 2048) {
      ((unsigned short*)out)[(size_t)rr * 2048 + ((cc - 1024) << 1) + 1] = f2bf(x);
    } else {
      ((unsigned short*)out2)[(size_t)rr * 1024 + (cc - 2048)] = f2bf(x);
    }
  } else if (EPI == EPI_GELU) {
    x = 0.5f * x * (1.f + erff(x * 0.70710678118654752f));
    ((unsigned short*)out)[(size_t)rr * N + cc] = f2bf(x);
  } else if (EPI == EPI_RES) {
    x += ((const float*)aux)[(size_t)rr * N + cc];
    ((unsigned short*)out)[(size_t)rr * N + cc] = f2bf(x);
  } else if (EPI == EPI_HEAD) {
    x *= bf2f(((const unsigned short*)aux)[(size_t)rr * 1024 + cc]);
    ((float*)out)[(size_t)rr * N + cc] = x;
  } else {
    ((float*)out)[(size_t)rr * N + cc] = x;
  }
}

// ---------------- 128x128 m97-structure GEMM (BK=32, 16KB LDS, high occupancy) ----------------
template<int EPI, int DIAG>
__global__ __launch_bounds__(256)
void gemm_bt(const unsigned short* __restrict__ A, int lda,
             const unsigned short* __restrict__ Bt, int ldb,
             const float* __restrict__ bias, const void* __restrict__ aux,
             void* __restrict__ out, void* __restrict__ out2, int M, int N, int K) {
  __shared__ unsigned short lA[128 * 32];
  __shared__ unsigned short lB[128 * 32];
  const int tid = threadIdx.x;
  const int w = tid >> 6, l = tid & 63;
  // T1 XCD swizzle (nwg % 8 == 0)
  const int gx = gridDim.x, nwg = gx * gridDim.y;
  const int o = blockIdx.y * gx + blockIdx.x;
  const int lin = (o & 7) * (nwg >> 3) + (o >> 3);
  const int row0 = (lin / gx) * 128, col0 = (lin % gx) * 128;
  const int kOff = DIAG ? col0 : 0;

  const int rA0 = w * 16 + (l >> 2);
  const int rA1 = (4 + w) * 16 + (l >> 2);
  const int koff = (l & 3) * 8;
  const unsigned short* gA0 = A + (size_t)(row0 + rA0) * lda + kOff + koff;
  const unsigned short* gA1 = A + (size_t)(row0 + rA1) * lda + kOff + koff;
  const unsigned short* gB0 = Bt + (size_t)(col0 + rA0) * ldb + koff;
  const unsigned short* gB1 = Bt + (size_t)(col0 + rA1) * ldb + koff;
  unsigned short* lA0 = lA + w * 512;
  unsigned short* lA1 = lA + (4 + w) * 512;
  unsigned short* lB0 = lB + w * 512;
  unsigned short* lB1 = lB + (4 + w) * 512;

  const int wr = (w >> 1) * 64, wc = (w & 1) * 64;
  f32x4 acc[4][4];
  #pragma unroll
  for (int m = 0; m < 4; m++)
    #pragma unroll
    for (int n = 0; n < 4; n++) acc[m][n] = (f32x4){0.f, 0.f, 0.f, 0.f};

  const int arow = wr + (l & 15);
  const int brow = wc + (l & 15);
  const int kg = (l >> 4) * 8;

  for (int kt = 0; kt < K; kt += 32) {
    __syncthreads();
    gload16(gA0 + kt, lA0);
    gload16(gA1 + kt, lA1);
    gload16(gB0 + kt, lB0);
    gload16(gB1 + kt, lB1);
    __syncthreads();
    short8 af[4], bfr[4];
    #pragma unroll
    for (int m = 0; m < 4; m++) af[m]  = *(const short8*)(lA + (arow + m * 16) * 32 + kg);
    #pragma unroll
    for (int n = 0; n < 4; n++) bfr[n] = *(const short8*)(lB + (brow + n * 16) * 32 + kg);
    #pragma unroll
    for (int m = 0; m < 4; m++)
      #pragma unroll
      for (int n = 0; n < 4; n++)
        acc[m][n] = __builtin_amdgcn_mfma_f32_16x16x32_bf16(af[m], bfr[n], acc[m][n], 0, 0, 0);
  }

  const int er = row0 + wr + ((l >> 4) << 2);
  const int ec = col0 + wc + (l & 15);
  #pragma unroll
  for (int m = 0; m < 4; m++)
    #pragma unroll
    for (int n = 0; n < 4; n++)
      #pragma unroll
      for (int j = 0; j < 4; j++)
        epi_store<EPI>(acc[m][n][j], er + m * 16 + j, ec + n * 16, N, bias, aux, out, out2);
}

// ---------------- chunked affine scan (bf16 inputs, f32 accum) ----------------
__global__ void scan_p1(const unsigned short* __restrict__ ab16, float* __restrict__ aggA, float* __restrict__ aggB) {
  int id = blockIdx.x * 256 + threadIdx.x;
  int c = id & 1023;
  int chunk = (id >> 10) & (NCH - 1);
  int bb = id >> 14;
  const unsigned short* base = ab16 + (size_t)(bb * L_ + chunk * CLEN) * 2048 + 2 * c;
  float Aa = 1.f, Bv = 0.f;
  #pragma unroll 4
  for (int t = 0; t < CLEN; ++t) {
    unsigned int v = *(const unsigned int*)(base + (size_t)t * 2048);
    float a = bf2f(v & 0xffffu);
    float b = bf2f(v >> 16);
    Aa *= a;
    Bv = a * Bv + b;
  }
  int o = (chunk * B_ + bb) * 1024 + c;
  aggA[o] = Aa; aggB[o] = Bv;
}

__global__ void scan_p2(const float* __restrict__ aggA, const float* __restrict__ aggB,
                        float* __restrict__ hinit) {
  int id = blockIdx.x * 256 + threadIdx.x;
  float hc = 0.f;
  for (int ch = 0; ch < NCH; ++ch) {
    int o = ch * 4096 + id;
    hinit[o] = hc;
    hc = aggA[o] * hc + aggB[o];
  }
}

__global__ void scan_p3(const unsigned short* __restrict__ ab16, const float* __restrict__ hinit,
                        unsigned short* __restrict__ hb16) {
  int id = blockIdx.x * 256 + threadIdx.x;
  int c = id & 1023;
  int chunk = (id >> 10) & (NCH - 1);
  int bb = id >> 14;
  const unsigned short* base = ab16 + (size_t)(bb * L_ + chunk * CLEN) * 2048 + 2 * c;
  unsigned short* hb = hb16 + (size_t)(bb * L_ + chunk * CLEN) * 1024;
  float h = hinit[chunk * 4096 + bb * 1024 + c];
  #pragma unroll 4
  for (int t = 0; t < CLEN; ++t) {
    unsigned int v = *(const unsigned int*)(base + (size_t)t * 2048);
    float a = bf2f(v & 0xffffu);
    float b = bf2f(v >> 16);
    h = a * h + b;
    hb[(size_t)t * 1024 + c] = f2bf(h);
  }
}

// ---------------- u = z + LN(z); outputs f32 + bf16 ----------------
__global__ __launch_bounds__(256)
void ln_res(const float* __restrict__ z, const float* __restrict__ lg, const float* __restrict__ lb,
            float* __restrict__ u32, unsigned short* __restrict__ u16) {
  int row = blockIdx.x;
  int t = threadIdx.x;
  const float4 zv = *(const float4*)(z + (size_t)row * 1024 + t * 4);
  float s = zv.x + zv.y + zv.z + zv.w;
  float sq = zv.x * zv.x + zv.y * zv.y + zv.z * zv.z + zv.w * zv.w;
  #pragma unroll
  for (int o = 32; o > 0; o >>= 1) { s += __shfl_down(s, o); sq += __shfl_down(sq, o); }
  __shared__ float ps[4], pq[4];
  if ((t & 63) == 0) { ps[t >> 6] = s; pq[t >> 6] = sq; }
  __syncthreads();
  s = ps[0] + ps[1] + ps[2] + ps[3];
  sq = pq[0] + pq[1] + pq[2] + pq[3];
  float mu = s * (1.f / 1024.f);
  float var = sq * (1.f / 1024.f) - mu * mu;
  float rs = rsqrtf(var + 1e-5f);
  const float4 gv = *(const float4*)(lg + t * 4);
  const float4 bv = *(const float4*)(lb + t * 4);
  float4 o;
  o.x = zv.x + (zv.x - mu) * rs * gv.x + bv.x;
  o.y = zv.y + (zv.y - mu) * rs * gv.y + bv.y;
  o.z = zv.z + (zv.z - mu) * rs * gv.z + bv.z;
  o.w = zv.w + (zv.w - mu) * rs * gv.w + bv.w;
  *(float4*)(u32 + (size_t)row * 1024 + t * 4) = o;
  ushort4 ob; ob.x = f2bf(o.x); ob.y = f2bf(o.y); ob.z = f2bf(o.z); ob.w = f2bf(o.w);
  *(ushort4*)(u16 + (size_t)row * 1024 + t * 4) = ob;
}

extern "C" void kernel_launch(void* const* d_in, const int* in_sizes, int n_in,
                              void* d_out, int out_size, void* d_ws, size_t ws_size,
                              hipStream_t stream) {
  const float* emb    = (const float*)d_in[0];
  const float* Wa     = (const float*)d_in[1];
  const float* ba     = (const float*)d_in[2];
  const float* Wb     = (const float*)d_in[3];
  const float* bb     = (const float*)d_in[4];
  const float* WD     = (const float*)d_in[5];
  const float* bD     = (const float*)d_in[6];
  const float* WC     = (const float*)d_in[7];
  const float* bC     = (const float*)d_in[8];
  const float* ffn1_w = (const float*)d_in[9];
  const float* ffn1_b = (const float*)d_in[10];
  const float* ffn2_w = (const float*)d_in[11];
  const float* ffn2_b = (const float*)d_in[12];
  const float* proj_w = (const float*)d_in[13];
  const float* proj_b = (const float*)d_in[14];
  const float* ln_g   = (const float*)d_in[15];
  const float* ln_b   = (const float*)d_in[16];

  char* p = (char*)d_ws;
  auto alloc = [&](size_t bytes) { char* r = p; p += (bytes + 255) & ~(size_t)255; return (void*)r; };

  unsigned short* ab16 = (unsigned short*)alloc((size_t)ROWS * 2048 * 2);  // 32MB (a,b) pairs
  unsigned short* d16  = (unsigned short*)alloc((size_t)ROWS * 1024 * 2);  // 16MB d gate
  unsigned short* hb16 = (unsigned short*)alloc((size_t)ROWS * 1024 * 2);  // 16MB scan h
  float* zbuf  = (float*)alloc((size_t)ROWS * 1024 * 4);                   // 32MB
  float* u32   = (float*)alloc((size_t)ROWS * 1024 * 4);
  unsigned short* u16  = (unsigned short*)alloc((size_t)ROWS * 1024 * 2);
  unsigned short* embb = (unsigned short*)alloc((size_t)ROWS * 1024 * 2);
  unsigned short* wcat = (unsigned short*)alloc((size_t)3072 * 1024 * 2);
  unsigned short* f1t  = (unsigned short*)alloc((size_t)4096 * 1024 * 2);
  unsigned short* f2t  = (unsigned short*)alloc((size_t)4096 * 1024 * 2);
  unsigned short* pjt  = (unsigned short*)alloc((size_t)1024 * 1024 * 2);
  unsigned short* wcd  = (unsigned short*)alloc((size_t)1024 * 128 * 2);
  float* biascat = (float*)alloc(3072 * 4);
  float* aggA  = (float*)alloc(65536 * 4);
  float* aggB  = (float*)alloc(65536 * 4);
  float* hinit = (float*)alloc(65536 * 4);
  // aliases (disjoint lifetimes):
  unsigned short* gbuf = ab16;                  // [ROWS][4096] bf16, written by FFN1 (after head)
  unsigned short* vbuf = (unsigned short*)zbuf; // [ROWS][1024] bf16, written by FFN2 (after ln_res)

  dim3 tb(32, 8);
  cast_f32_bf16<<<ROWS * 1024 / 1024, 256, 0, stream>>>(emb, embb, ROWS * 1024);
  build_bias<<<12, 256, 0, stream>>>(ba, bb, bD, biascat);
  build_wcd<<<1024 * 128 / 256, 256, 0, stream>>>(WC, wcd);
  transpose_cast<<<dim3(E_ / 32, DH_ / 32, H_), tb, 0, stream>>>(Wa, wcat, E_, DH_, 0);
  transpose_cast<<<dim3(E_ / 32, DH_ / 32, H_), tb, 0, stream>>>(Wb, wcat, E_, DH_, 1024);
  transpose_cast<<<dim3(E_ / 32, DH_ / 32, H_), tb, 0, stream>>>(WD, wcat, E_, DH_, 2048);
  transpose_cast<<<dim3(1024 / 32, 4096 / 32, 1), tb, 0, stream>>>(ffn1_w, f1t, 1024, 4096, 0);
  transpose_cast<<<dim3(4096 / 32, 1024 / 32, 1), tb, 0, stream>>>(ffn2_w, f2t, 4096, 1024, 0);
  transpose_cast<<<dim3(1024 / 32, 1024 / 32, 1), tb, 0, stream>>>(proj_w, pjt, 1024, 1024, 0);

  // G1: [8192,1024]x[1024,3072] -> ab16 + d16   [128^2, 1536 wg ~5 blk/CU]
  gemm_bt<EPI_GATES, 0><<<dim3(3072 / 128, ROWS / 128), 256, 0, stream>>>(
      embb, 1024, wcat, 1024, biascat, nullptr, ab16, d16, ROWS, 3072, 1024);

  scan_p1<<<65536 / 256, 256, 0, stream>>>(ab16, aggA, aggB);
  scan_p2<<<4096 / 256, 256, 0, stream>>>(aggA, aggB, hinit);
  scan_p3<<<65536 / 256, 256, 0, stream>>>(ab16, hinit, hb16);

  // head: z = (h @ WC_diag + bC) * d ; K=128 diag window per col-block
  gemm_bt<EPI_HEAD, 1><<<dim3(1024 / 128, ROWS / 128), 256, 0, stream>>>(
      hb16, 1024, wcd, 128, bC, d16, zbuf, nullptr, ROWS, 1024, 128);

  ln_res<<<ROWS, 256, 0, stream>>>(zbuf, ln_g, ln_b, u32, u16);

  // FFN1: [8192,1024]x[1024,4096] -> gelu -> gbuf   [128^2, 2048 wg ~5 blk/CU]
  gemm_bt<EPI_GELU, 0><<<dim3(4096 / 128, ROWS / 128), 256, 0, stream>>>(
      u16, 1024, f1t, 1024, ffn1_b, nullptr, gbuf, nullptr, ROWS, 4096, 1024);
  // FFN2: [8192,4096]x[4096,1024] + u -> vbuf       [128^2, 512 wg]
  gemm_bt<EPI_RES, 0><<<dim3(1024 / 128, ROWS / 128), 256, 0, stream>>>(
      gbuf, 4096, f2t, 4096, ffn2_b, u32, vbuf, nullptr, ROWS, 1024, 4096);
  // proj: [8192,1024]x[1024,1024] -> d_out (f32)    [128^2, 512 wg]
  gemm_bt<EPI_OUT, 0><<<dim3(1024 / 128, ROWS / 128), 256, 0, stream>>>(
      vbuf, 1024, pjt, 1024, proj_b, nullptr, (float*)d_out, nullptr, ROWS, 1024, 1024);
}